// Round 3
// baseline (955.752 us; speedup 1.0000x reference)
//
#include <hip/hip_runtime.h>
#include <math.h>

#define N_NODES   100000
#define N_FEAT    512
#define HIDDEN    16
#define N_CLASSES 7
#define N_EDGES   3200000

// bucket = dst >> 7  (128 nodes per bucket)
#define BSHIFT 7
#define BNODES 128
#define BMASK  127
#define NBUK   782            // ceil(100000/128)
#define CHUNK  16384
#define NCHUNK 196            // ceil(3200000/16384)

__device__ __forceinline__ float bf_lo(unsigned int p) { return __uint_as_float(p << 16); }
__device__ __forceinline__ float bf_hi(unsigned int p) { return __uint_as_float(p & 0xffff0000u); }
__device__ __forceinline__ unsigned int pack_bf2(float a, float b) {
    unsigned int ua = __float_as_uint(a); ua += 0x7fffu + ((ua >> 16) & 1u);
    unsigned int ub = __float_as_uint(b); ub += 0x7fffu + ((ub >> 16) & 1u);
    return (ua >> 16) | (ub & 0xffff0000u);
}

// ---------- bucket histogram / scan / scatter (counting sort by dst bucket) ----------

__global__ void k_zero_b(int* __restrict__ btot) {
    int i = threadIdx.x;
    if (i < NBUK) btot[i] = 0;
}

__global__ __launch_bounds__(256) void k_bhist(const int* __restrict__ dst,
                                               int* __restrict__ btot) {
    __shared__ int h[NBUK];
    int tid = threadIdx.x;
    for (int i = tid; i < NBUK; i += 256) h[i] = 0;
    __syncthreads();
    int base = blockIdx.x * CHUNK;
    for (int i = tid; i < CHUNK; i += 256) {
        int e = base + i;
        if (e < N_EDGES) atomicAdd(&h[dst[e] >> BSHIFT], 1);
    }
    __syncthreads();
    for (int i = tid; i < NBUK; i += 256)
        if (h[i]) atomicAdd(&btot[i], h[i]);
}

__global__ void k_bscan(const int* __restrict__ btot, int* __restrict__ gbase,
                        int* __restrict__ gcur) {
    __shared__ int sd[1024];
    int t = threadIdx.x;
    int v = (t < NBUK) ? btot[t] : 0;
    sd[t] = v;
    __syncthreads();
    for (int off = 1; off < 1024; off <<= 1) {
        int a = (t >= off) ? sd[t - off] : 0;
        __syncthreads();
        sd[t] += a;
        __syncthreads();
    }
    if (t < NBUK) {
        int ex = sd[t] - v;  // exclusive
        gbase[t] = ex;
        gcur[t]  = ex;
    }
}

__global__ __launch_bounds__(256) void k_bscatter(const int* __restrict__ src,
                                                  const int* __restrict__ dst,
                                                  int* __restrict__ gcur,
                                                  int* __restrict__ entries) {
    __shared__ int h[NBUK];
    __shared__ int lb[NBUK];
    int tid = threadIdx.x;
    for (int i = tid; i < NBUK; i += 256) h[i] = 0;
    __syncthreads();
    int base = blockIdx.x * CHUNK;
    for (int i = tid; i < CHUNK; i += 256) {
        int e = base + i;
        if (e < N_EDGES) atomicAdd(&h[dst[e] >> BSHIFT], 1);
    }
    __syncthreads();
    for (int i = tid; i < NBUK; i += 256) {
        int c = h[i];
        lb[i] = c ? atomicAdd(&gcur[i], c) : 0;
        h[i] = 0;  // reuse as local cursor
    }
    __syncthreads();
    for (int i = tid; i < CHUNK; i += 256) {
        int e = base + i;
        if (e < N_EDGES) {
            int d = dst[e];
            int b = d >> BSHIFT;
            int pos = lb[b] + atomicAdd(&h[b], 1);
            entries[pos] = src[e] | ((d & BMASK) << 17);  // src<2^17, loc 7 bits
        }
    }
}

// ---------- per-node dinv from bucket entries ----------

__global__ __launch_bounds__(256) void k_dinv(const int* __restrict__ entries,
                                              const int* __restrict__ btot,
                                              const int* __restrict__ gbase,
                                              float* __restrict__ dinv) {
    __shared__ int c[BNODES];
    int tid = threadIdx.x;
    if (tid < BNODES) c[tid] = 0;
    __syncthreads();
    int bk = blockIdx.x;
    int cnt = btot[bk], base = gbase[bk];
    for (int i = tid; i < cnt; i += 256)
        atomicAdd(&c[entries[base + i] >> 17], 1);
    __syncthreads();
    if (tid < BNODES) {
        int n = bk * BNODES + tid;
        if (n < N_NODES) dinv[n] = rsqrtf((float)(c[tid] + 1));  // +1 self-loop
    }
}

// ---------- GEMM1: hs1 = bf16( dinv ⊙ (x @ W1) ), 16 lanes per row ----------

__global__ __launch_bounds__(256) void k_gemm1(const float* __restrict__ x,
                                               const float* __restrict__ W1,
                                               const float* __restrict__ dinv,
                                               unsigned int* __restrict__ hs1b) {
    __shared__ float wl[512 * 17];
    int tid = threadIdx.x;
    for (int idx = tid; idx < N_FEAT * HIDDEN; idx += 256) {
        int col = idx >> 4, o = idx & 15;
        wl[col * 17 + o] = W1[idx];
    }
    __syncthreads();

    int lane = tid & 15;
    int row  = blockIdx.x * 16 + (tid >> 4);
    const float4* xr = (const float4*)(x + (size_t)row * N_FEAT);

    float acc[16];
#pragma unroll
    for (int o = 0; o < 16; o++) acc[o] = 0.f;

#pragma unroll
    for (int i = 0; i < 8; i++) {
        int col = i * 64 + lane * 4;
        float4 xv = xr[col >> 2];
#pragma unroll
        for (int j = 0; j < 4; j++) {
            float xj = (&xv.x)[j];
            const float* wr = &wl[(col + j) * 17];
#pragma unroll
            for (int o = 0; o < 16; o++) acc[o] += xj * wr[o];
        }
    }

#pragma unroll
    for (int m = 1; m < 16; m <<= 1) {
#pragma unroll
        for (int o = 0; o < 16; o++) acc[o] += __shfl_xor(acc[o], m, 64);
    }

    if (lane == 0) {
        float dn = dinv[row];
        uint4* outp = (uint4*)(hs1b + (size_t)row * 8);
        outp[0] = make_uint4(pack_bf2(acc[0] * dn,  acc[1] * dn),
                             pack_bf2(acc[2] * dn,  acc[3] * dn),
                             pack_bf2(acc[4] * dn,  acc[5] * dn),
                             pack_bf2(acc[6] * dn,  acc[7] * dn));
        outp[1] = make_uint4(pack_bf2(acc[8] * dn,  acc[9] * dn),
                             pack_bf2(acc[10] * dn, acc[11] * dn),
                             pack_bf2(acc[12] * dn, acc[13] * dn),
                             pack_bf2(acc[14] * dn, acc[15] * dn));
    }
}

// ---------- layer1 aggregate + bias + relu + W2: hs2 = bf16( dinv ⊙ (relu(...)@W2) ) ----------
// 512 threads, 8 lanes/edge (bf16x2 per lane), 4-deep pipeline, LDS fp32 atomics.

#define G1 64  // edge groups per block (512/8)

__global__ __launch_bounds__(512) void k_bagg1(const unsigned int* __restrict__ hs1b,
                                               const int* __restrict__ entries,
                                               const int* __restrict__ btot,
                                               const int* __restrict__ gbase,
                                               const float* __restrict__ dinv,
                                               const float* __restrict__ b1,
                                               const float* __restrict__ W2,
                                               unsigned int* __restrict__ hs2b) {
    __shared__ float acc[BNODES * 17];
    __shared__ float w2l[HIDDEN * N_CLASSES];
    int tid = threadIdx.x;
    if (tid < HIDDEN * N_CLASSES) w2l[tid] = W2[tid];
    for (int i = tid; i < BNODES * 17; i += 512) acc[i] = 0.f;
    __syncthreads();

    int bk = blockIdx.x;
    int cnt = btot[bk], base = gbase[bk];
    int g = tid >> 3;   // edge group 0..63
    int j = tid & 7;    // lane in group: channels 2j, 2j+1

    int e = g;
    for (; e + 3 * G1 < cnt; e += 4 * G1) {
        int en0 = entries[base + e];
        int en1 = entries[base + e + G1];
        int en2 = entries[base + e + 2 * G1];
        int en3 = entries[base + e + 3 * G1];
        unsigned int v0 = hs1b[(size_t)(en0 & 0x1FFFF) * 8 + j];
        unsigned int v1 = hs1b[(size_t)(en1 & 0x1FFFF) * 8 + j];
        unsigned int v2 = hs1b[(size_t)(en2 & 0x1FFFF) * 8 + j];
        unsigned int v3 = hs1b[(size_t)(en3 & 0x1FFFF) * 8 + j];
        float* a0 = &acc[(en0 >> 17) * 17 + 2 * j];
        float* a1 = &acc[(en1 >> 17) * 17 + 2 * j];
        float* a2 = &acc[(en2 >> 17) * 17 + 2 * j];
        float* a3 = &acc[(en3 >> 17) * 17 + 2 * j];
        atomicAdd(a0, bf_lo(v0)); atomicAdd(a0 + 1, bf_hi(v0));
        atomicAdd(a1, bf_lo(v1)); atomicAdd(a1 + 1, bf_hi(v1));
        atomicAdd(a2, bf_lo(v2)); atomicAdd(a2 + 1, bf_hi(v2));
        atomicAdd(a3, bf_lo(v3)); atomicAdd(a3 + 1, bf_hi(v3));
    }
    for (; e < cnt; e += G1) {
        int en = entries[base + e];
        unsigned int v = hs1b[(size_t)(en & 0x1FFFF) * 8 + j];
        float* a = &acc[(en >> 17) * 17 + 2 * j];
        atomicAdd(a, bf_lo(v)); atomicAdd(a + 1, bf_hi(v));
    }
    __syncthreads();

    if (tid < BNODES) {
        int n = bk * BNODES + tid;
        if (n < N_NODES) {
            float dn = dinv[n];
            const uint4* hp = (const uint4*)(hs1b + (size_t)n * 8);
            uint4 p0 = hp[0], p1 = hp[1];
            float self[16] = {bf_lo(p0.x), bf_hi(p0.x), bf_lo(p0.y), bf_hi(p0.y),
                              bf_lo(p0.z), bf_hi(p0.z), bf_lo(p0.w), bf_hi(p0.w),
                              bf_lo(p1.x), bf_hi(p1.x), bf_lo(p1.y), bf_hi(p1.y),
                              bf_lo(p1.z), bf_hi(p1.z), bf_lo(p1.w), bf_hi(p1.w)};
            float z[16];
#pragma unroll
            for (int k = 0; k < 16; k++)
                z[k] = fmaxf(dn * (acc[tid * 17 + k] + self[k]) + b1[k], 0.f);
            float t[7];
#pragma unroll
            for (int q = 0; q < 7; q++) t[q] = 0.f;
#pragma unroll
            for (int k = 0; k < 16; k++) {
#pragma unroll
                for (int q = 0; q < 7; q++) t[q] += z[k] * w2l[k * 7 + q];
            }
            uint4* o = (uint4*)(hs2b + (size_t)n * 4);
            o[0] = make_uint4(pack_bf2(dn * t[0], dn * t[1]),
                              pack_bf2(dn * t[2], dn * t[3]),
                              pack_bf2(dn * t[4], dn * t[5]),
                              pack_bf2(dn * t[6], 0.f));
        }
    }
}

// ---------- layer2 aggregate + bias + log_softmax ----------
// 512 threads, 4 lanes/edge (bf16x2 per lane), 4-deep pipeline.

#define G2 128  // edge groups per block (512/4)

__global__ __launch_bounds__(512) void k_bagg2(const unsigned int* __restrict__ hs2b,
                                               const int* __restrict__ entries,
                                               const int* __restrict__ btot,
                                               const int* __restrict__ gbase,
                                               const float* __restrict__ dinv,
                                               const float* __restrict__ b2,
                                               float* __restrict__ out) {
    __shared__ float acc[BNODES * 9];
    int tid = threadIdx.x;
    for (int i = tid; i < BNODES * 9; i += 512) acc[i] = 0.f;
    __syncthreads();

    int bk = blockIdx.x;
    int cnt = btot[bk], base = gbase[bk];
    int g = tid >> 2;   // edge group 0..127
    int j = tid & 3;    // channels 2j, 2j+1

    int e = g;
    for (; e + 3 * G2 < cnt; e += 4 * G2) {
        int en0 = entries[base + e];
        int en1 = entries[base + e + G2];
        int en2 = entries[base + e + 2 * G2];
        int en3 = entries[base + e + 3 * G2];
        unsigned int v0 = hs2b[(size_t)(en0 & 0x1FFFF) * 4 + j];
        unsigned int v1 = hs2b[(size_t)(en1 & 0x1FFFF) * 4 + j];
        unsigned int v2 = hs2b[(size_t)(en2 & 0x1FFFF) * 4 + j];
        unsigned int v3 = hs2b[(size_t)(en3 & 0x1FFFF) * 4 + j];
        float* a0 = &acc[(en0 >> 17) * 9 + 2 * j];
        float* a1 = &acc[(en1 >> 17) * 9 + 2 * j];
        float* a2 = &acc[(en2 >> 17) * 9 + 2 * j];
        float* a3 = &acc[(en3 >> 17) * 9 + 2 * j];
        atomicAdd(a0, bf_lo(v0)); atomicAdd(a0 + 1, bf_hi(v0));
        atomicAdd(a1, bf_lo(v1)); atomicAdd(a1 + 1, bf_hi(v1));
        atomicAdd(a2, bf_lo(v2)); atomicAdd(a2 + 1, bf_hi(v2));
        atomicAdd(a3, bf_lo(v3)); atomicAdd(a3 + 1, bf_hi(v3));
    }
    for (; e < cnt; e += G2) {
        int en = entries[base + e];
        unsigned int v = hs2b[(size_t)(en & 0x1FFFF) * 4 + j];
        float* a = &acc[(en >> 17) * 9 + 2 * j];
        atomicAdd(a, bf_lo(v)); atomicAdd(a + 1, bf_hi(v));
    }
    __syncthreads();

    if (tid < BNODES) {
        int n = bk * BNODES + tid;
        if (n < N_NODES) {
            float dn = dinv[n];
            const uint4* hp = (const uint4*)(hs2b + (size_t)n * 4);
            uint4 p = hp[0];
            float self[7] = {bf_lo(p.x), bf_hi(p.x), bf_lo(p.y), bf_hi(p.y),
                             bf_lo(p.z), bf_hi(p.z), bf_lo(p.w)};
            float l[7];
#pragma unroll
            for (int q = 0; q < 7; q++)
                l[q] = dn * (acc[tid * 9 + q] + self[q]) + b2[q];
            float m = l[0];
#pragma unroll
            for (int q = 1; q < 7; q++) m = fmaxf(m, l[q]);
            float s = 0.f;
#pragma unroll
            for (int q = 0; q < 7; q++) s += expf(l[q] - m);
            float ls = m + logf(s);
            float* op = out + (size_t)n * 7;
#pragma unroll
            for (int q = 0; q < 7; q++) op[q] = l[q] - ls;
        }
    }
}

// ---------- launch ----------

extern "C" void kernel_launch(void* const* d_in, const int* in_sizes, int n_in,
                              void* d_out, int out_size, void* d_ws, size_t ws_size,
                              hipStream_t stream) {
    const float* x  = (const float*)d_in[0];
    const int*   ei = (const int*)d_in[1];
    const float* W1 = (const float*)d_in[2];
    const float* b1 = (const float*)d_in[3];
    const float* W2 = (const float*)d_in[4];
    const float* b2 = (const float*)d_in[5];
    float* out = (float*)d_out;

    const int* src = ei;
    const int* dst = ei + N_EDGES;

    char* w = (char*)d_ws;
    int*          btot    = (int*)(w + 0);            //   3128 B
    int*          gbase   = (int*)(w + 3200);         //   3128 B
    int*          gcur    = (int*)(w + 6400);         //   3128 B
    float*        dinv    = (float*)(w + 9600);       // 400000 B
    unsigned int* hs1b    = (unsigned int*)(w + 409600);   // 3.2 MB (bf16x2)
    unsigned int* hs2b    = (unsigned int*)(w + 3609600);  // 1.6 MB (bf16x2)
    int*          entries = (int*)(w + 5209600);      // 12.8 MB  (total ~18 MB)

    k_zero_b  <<<1, 1024, 0, stream>>>(btot);
    k_bhist   <<<NCHUNK, 256, 0, stream>>>(dst, btot);
    k_bscan   <<<1, 1024, 0, stream>>>(btot, gbase, gcur);
    k_bscatter<<<NCHUNK, 256, 0, stream>>>(src, dst, gcur, entries);
    k_dinv    <<<NBUK, 256, 0, stream>>>(entries, btot, gbase, dinv);
    k_gemm1   <<<N_NODES / 16, 256, 0, stream>>>(x, W1, dinv, hs1b);
    k_bagg1   <<<NBUK, 512, 0, stream>>>(hs1b, entries, btot, gbase, dinv, b1, W2, hs2b);
    k_bagg2   <<<NBUK, 512, 0, stream>>>(hs2b, entries, btot, gbase, dinv, b2, out);
}

// Round 4
// 520.546 us; speedup vs baseline: 1.8361x; 1.8361x over previous
//
#include <hip/hip_runtime.h>
#include <math.h>

#define N_NODES   100000
#define N_FEAT    512
#define HIDDEN    16
#define N_CLASSES 7
#define N_EDGES   3200000

// bucket = dst >> 7  (128 nodes per bucket)
#define BSHIFT 7
#define BNODES 128
#define BMASK  127
#define NBUK   782            // ceil(100000/128)
#define CHUNK  16384
#define NCHUNK 196            // ceil(3200000/16384)
#define CAP    6144           // LDS stage cap per bucket (mean 4092, sigma~64 -> +32 sigma)

__device__ __forceinline__ float bf_lo(unsigned int p) { return __uint_as_float(p << 16); }
__device__ __forceinline__ float bf_hi(unsigned int p) { return __uint_as_float(p & 0xffff0000u); }
__device__ __forceinline__ unsigned int pack_bf2(float a, float b) {
    unsigned int ua = __float_as_uint(a); ua += 0x7fffu + ((ua >> 16) & 1u);
    unsigned int ub = __float_as_uint(b); ub += 0x7fffu + ((ub >> 16) & 1u);
    return (ua >> 16) | (ub & 0xffff0000u);
}

// ---------- bucket histogram / scan / scatter (counting sort by dst bucket) ----------

__global__ void k_zero_b(int* __restrict__ btot) {
    int i = threadIdx.x;
    if (i < NBUK) btot[i] = 0;
}

__global__ __launch_bounds__(256) void k_bhist(const int* __restrict__ dst,
                                               int* __restrict__ btot) {
    __shared__ int h[NBUK];
    int tid = threadIdx.x;
    for (int i = tid; i < NBUK; i += 256) h[i] = 0;
    __syncthreads();
    int base = blockIdx.x * CHUNK;
    for (int i = tid; i < CHUNK; i += 256) {
        int e = base + i;
        if (e < N_EDGES) atomicAdd(&h[dst[e] >> BSHIFT], 1);
    }
    __syncthreads();
    for (int i = tid; i < NBUK; i += 256)
        if (h[i]) atomicAdd(&btot[i], h[i]);
}

__global__ void k_bscan(const int* __restrict__ btot, int* __restrict__ gbase,
                        int* __restrict__ gcur) {
    __shared__ int sd[1024];
    int t = threadIdx.x;
    int v = (t < NBUK) ? btot[t] : 0;
    sd[t] = v;
    __syncthreads();
    for (int off = 1; off < 1024; off <<= 1) {
        int a = (t >= off) ? sd[t - off] : 0;
        __syncthreads();
        sd[t] += a;
        __syncthreads();
    }
    if (t < NBUK) {
        int ex = sd[t] - v;  // exclusive
        gbase[t] = ex;
        gcur[t]  = ex;
    }
}

__global__ __launch_bounds__(256) void k_bscatter(const int* __restrict__ src,
                                                  const int* __restrict__ dst,
                                                  int* __restrict__ gcur,
                                                  int* __restrict__ entries) {
    __shared__ int h[NBUK];
    __shared__ int lb[NBUK];
    int tid = threadIdx.x;
    for (int i = tid; i < NBUK; i += 256) h[i] = 0;
    __syncthreads();
    int base = blockIdx.x * CHUNK;
    for (int i = tid; i < CHUNK; i += 256) {
        int e = base + i;
        if (e < N_EDGES) atomicAdd(&h[dst[e] >> BSHIFT], 1);
    }
    __syncthreads();
    for (int i = tid; i < NBUK; i += 256) {
        int c = h[i];
        lb[i] = c ? atomicAdd(&gcur[i], c) : 0;
        h[i] = 0;  // reuse as local cursor
    }
    __syncthreads();
    for (int i = tid; i < CHUNK; i += 256) {
        int e = base + i;
        if (e < N_EDGES) {
            int d = dst[e];
            int b = d >> BSHIFT;
            int pos = lb[b] + atomicAdd(&h[b], 1);
            entries[pos] = src[e] | ((d & BMASK) << 17);  // src<2^17, loc 7 bits
        }
    }
}

// ---------- in-LDS node-granular counting sort per bucket ----------
// After this, entries[base..base+cnt) holds plain src ids sorted by dst node,
// nodeptr[n]..nodeptr[n+1] delimits node n's edges, dinv[n] = rsqrt(deg+1).

__global__ __launch_bounds__(512) void k_nodesort(int* __restrict__ entries,
                                                  const int* __restrict__ btot,
                                                  const int* __restrict__ gbase,
                                                  float* __restrict__ dinv,
                                                  int* __restrict__ nodeptr) {
    __shared__ int ebuf[CAP];
    __shared__ int hcnt[BNODES];
    __shared__ int hincl[BNODES];
    __shared__ int hcur[BNODES];
    int tid = threadIdx.x;
    int bk = blockIdx.x;
    int cnt = btot[bk], base = gbase[bk];
    if (cnt > CAP) cnt = CAP;  // statistically impossible; guards LDS
    if (tid < BNODES) hcnt[tid] = 0;
    __syncthreads();
    for (int i = tid; i < cnt; i += 512) {
        int en = entries[base + i];
        ebuf[i] = en;
        atomicAdd(&hcnt[en >> 17], 1);
    }
    __syncthreads();
    if (tid < BNODES) hincl[tid] = hcnt[tid];
    __syncthreads();
    for (int off = 1; off < BNODES; off <<= 1) {
        int v = 0;
        if (tid < BNODES && tid >= off) v = hincl[tid - off];
        __syncthreads();
        if (tid < BNODES) hincl[tid] += v;
        __syncthreads();
    }
    if (tid < BNODES) {
        int excl = hincl[tid] - hcnt[tid];
        hcur[tid] = excl;
        int n = bk * BNODES + tid;
        if (n < N_NODES) {
            nodeptr[n] = base + excl;
            dinv[n]    = rsqrtf((float)(hcnt[tid] + 1));  // +1 self-loop
        } else if (n == N_NODES) {
            nodeptr[n] = base + excl;  // sentinel == N_EDGES
        }
    }
    __syncthreads();
    for (int i = tid; i < cnt; i += 512) {
        int en = ebuf[i];
        int pos = atomicAdd(&hcur[en >> 17], 1);
        entries[base + pos] = en & 0x1FFFF;  // plain src id
    }
}

// ---------- GEMM1: hs1 = bf16( dinv ⊙ (x @ W1) ), 16 lanes per row ----------

__global__ __launch_bounds__(256) void k_gemm1(const float* __restrict__ x,
                                               const float* __restrict__ W1,
                                               const float* __restrict__ dinv,
                                               unsigned int* __restrict__ hs1b) {
    __shared__ float wl[512 * 17];
    int tid = threadIdx.x;
    for (int idx = tid; idx < N_FEAT * HIDDEN; idx += 256) {
        int col = idx >> 4, o = idx & 15;
        wl[col * 17 + o] = W1[idx];
    }
    __syncthreads();

    int lane = tid & 15;
    int row  = blockIdx.x * 16 + (tid >> 4);
    const float4* xr = (const float4*)(x + (size_t)row * N_FEAT);

    float acc[16];
#pragma unroll
    for (int o = 0; o < 16; o++) acc[o] = 0.f;

#pragma unroll
    for (int i = 0; i < 8; i++) {
        int col = i * 64 + lane * 4;
        float4 xv = xr[col >> 2];
#pragma unroll
        for (int j = 0; j < 4; j++) {
            float xj = (&xv.x)[j];
            const float* wr = &wl[(col + j) * 17];
#pragma unroll
            for (int o = 0; o < 16; o++) acc[o] += xj * wr[o];
        }
    }

#pragma unroll
    for (int m = 1; m < 16; m <<= 1) {
#pragma unroll
        for (int o = 0; o < 16; o++) acc[o] += __shfl_xor(acc[o], m, 64);
    }

    if (lane == 0) {
        float dn = dinv[row];
        uint4* outp = (uint4*)(hs1b + (size_t)row * 8);
        outp[0] = make_uint4(pack_bf2(acc[0] * dn,  acc[1] * dn),
                             pack_bf2(acc[2] * dn,  acc[3] * dn),
                             pack_bf2(acc[4] * dn,  acc[5] * dn),
                             pack_bf2(acc[6] * dn,  acc[7] * dn));
        outp[1] = make_uint4(pack_bf2(acc[8] * dn,  acc[9] * dn),
                             pack_bf2(acc[10] * dn, acc[11] * dn),
                             pack_bf2(acc[12] * dn, acc[13] * dn),
                             pack_bf2(acc[14] * dn, acc[15] * dn));
    }
}

// ---------- layer1 aggregate (atomic-free) + bias + relu + W2 ----------
// 512 threads = 64 node-groups x 8 lanes (2 bf16 channels per lane); 2 passes.

__global__ __launch_bounds__(512) void k_agg1(const unsigned int* __restrict__ hs1b,
                                              const int* __restrict__ srt,
                                              const int* __restrict__ nodeptr,
                                              const float* __restrict__ dinv,
                                              const float* __restrict__ b1,
                                              const float* __restrict__ W2,
                                              unsigned int* __restrict__ hs2b) {
    __shared__ float w2l[HIDDEN * N_CLASSES];
    __shared__ float b1l[HIDDEN];
    int tid = threadIdx.x;
    if (tid < HIDDEN * N_CLASSES) w2l[tid] = W2[tid];
    if (tid < HIDDEN) b1l[tid] = b1[tid];
    __syncthreads();

    int bk = blockIdx.x;
    int g = tid >> 3, j = tid & 7;

#pragma unroll
    for (int rep = 0; rep < 2; rep++) {
        int l = g + rep * 64;
        int n = bk * BNODES + l;
        float t[7] = {0.f, 0.f, 0.f, 0.f, 0.f, 0.f, 0.f};
        float dn = 0.f;
        if (n < N_NODES) {
            int p0 = nodeptr[n], p1 = nodeptr[n + 1];
            float aL0 = 0, aH0 = 0, aL1 = 0, aH1 = 0;
            float aL2 = 0, aH2 = 0, aL3 = 0, aH3 = 0;
            int e = p0;
            for (; e + 4 <= p1; e += 4) {
                int s0 = srt[e], s1 = srt[e + 1], s2 = srt[e + 2], s3 = srt[e + 3];
                unsigned int v0 = hs1b[(size_t)s0 * 8 + j];
                unsigned int v1 = hs1b[(size_t)s1 * 8 + j];
                unsigned int v2 = hs1b[(size_t)s2 * 8 + j];
                unsigned int v3 = hs1b[(size_t)s3 * 8 + j];
                aL0 += bf_lo(v0); aH0 += bf_hi(v0);
                aL1 += bf_lo(v1); aH1 += bf_hi(v1);
                aL2 += bf_lo(v2); aH2 += bf_hi(v2);
                aL3 += bf_lo(v3); aH3 += bf_hi(v3);
            }
            for (; e < p1; e++) {
                unsigned int v = hs1b[(size_t)srt[e] * 8 + j];
                aL0 += bf_lo(v); aH0 += bf_hi(v);
            }
            unsigned int sv = hs1b[(size_t)n * 8 + j];  // self-loop
            float accL = aL0 + aL1 + aL2 + aL3 + bf_lo(sv);
            float accH = aH0 + aH1 + aH2 + aH3 + bf_hi(sv);
            dn = dinv[n];
            float z0 = fmaxf(dn * accL + b1l[2 * j],     0.f);
            float z1 = fmaxf(dn * accH + b1l[2 * j + 1], 0.f);
            const float* wr0 = &w2l[(2 * j) * 7];
            const float* wr1 = &w2l[(2 * j + 1) * 7];
#pragma unroll
            for (int q = 0; q < 7; q++) t[q] = z0 * wr0[q] + z1 * wr1[q];
        }
#pragma unroll
        for (int m = 1; m < 8; m <<= 1) {
#pragma unroll
            for (int q = 0; q < 7; q++) t[q] += __shfl_xor(t[q], m, 64);
        }
        if (j == 0 && n < N_NODES) {
            uint4* o = (uint4*)(hs2b + (size_t)n * 4);
            o[0] = make_uint4(pack_bf2(dn * t[0], dn * t[1]),
                              pack_bf2(dn * t[2], dn * t[3]),
                              pack_bf2(dn * t[4], dn * t[5]),
                              pack_bf2(dn * t[6], 0.f));
        }
    }
}

// ---------- layer2 aggregate (atomic-free) + bias + log_softmax ----------
// 512 threads = 128 node-groups x 4 lanes (2 channels per lane).

__global__ __launch_bounds__(512) void k_agg2(const unsigned int* __restrict__ hs2b,
                                              const int* __restrict__ srt,
                                              const int* __restrict__ nodeptr,
                                              const float* __restrict__ dinv,
                                              const float* __restrict__ b2,
                                              float* __restrict__ out) {
    int tid = threadIdx.x;
    int g = tid >> 2, j = tid & 3;
    int bk = blockIdx.x;
    int n = bk * BNODES + g;
    bool valid = (n < N_NODES);
    float lL = -3.4e38f, lH = -3.4e38f;
    if (valid) {
        int p0 = nodeptr[n], p1 = nodeptr[n + 1];
        float aL0 = 0, aH0 = 0, aL1 = 0, aH1 = 0;
        float aL2 = 0, aH2 = 0, aL3 = 0, aH3 = 0;
        int e = p0;
        for (; e + 4 <= p1; e += 4) {
            int s0 = srt[e], s1 = srt[e + 1], s2 = srt[e + 2], s3 = srt[e + 3];
            unsigned int v0 = hs2b[(size_t)s0 * 4 + j];
            unsigned int v1 = hs2b[(size_t)s1 * 4 + j];
            unsigned int v2 = hs2b[(size_t)s2 * 4 + j];
            unsigned int v3 = hs2b[(size_t)s3 * 4 + j];
            aL0 += bf_lo(v0); aH0 += bf_hi(v0);
            aL1 += bf_lo(v1); aH1 += bf_hi(v1);
            aL2 += bf_lo(v2); aH2 += bf_hi(v2);
            aL3 += bf_lo(v3); aH3 += bf_hi(v3);
        }
        for (; e < p1; e++) {
            unsigned int v = hs2b[(size_t)srt[e] * 4 + j];
            aL0 += bf_lo(v); aH0 += bf_hi(v);
        }
        unsigned int sv = hs2b[(size_t)n * 4 + j];  // self-loop
        float accL = aL0 + aL1 + aL2 + aL3 + bf_lo(sv);
        float accH = aH0 + aH1 + aH2 + aH3 + bf_hi(sv);
        float dn = dinv[n];
        lL = dn * accL + b2[2 * j];
        int c = 2 * j + 1;
        lH = (c < 7) ? (dn * accH + b2[c]) : -3.4e38f;
    }
    float m = fmaxf(lL, lH);
    m = fmaxf(m, __shfl_xor(m, 1, 64));
    m = fmaxf(m, __shfl_xor(m, 2, 64));
    float s = 0.f;
    if (valid) {
        s = expf(lL - m);
        if (2 * j + 1 < 7) s += expf(lH - m);
    }
    s += __shfl_xor(s, 1, 64);
    s += __shfl_xor(s, 2, 64);
    if (valid) {
        float ls = m + logf(s);
        out[(size_t)n * 7 + 2 * j] = lL - ls;
        if (2 * j + 1 < 7) out[(size_t)n * 7 + 2 * j + 1] = lH - ls;
    }
}

// ---------- launch ----------

extern "C" void kernel_launch(void* const* d_in, const int* in_sizes, int n_in,
                              void* d_out, int out_size, void* d_ws, size_t ws_size,
                              hipStream_t stream) {
    const float* x  = (const float*)d_in[0];
    const int*   ei = (const int*)d_in[1];
    const float* W1 = (const float*)d_in[2];
    const float* b1 = (const float*)d_in[3];
    const float* W2 = (const float*)d_in[4];
    const float* b2 = (const float*)d_in[5];
    float* out = (float*)d_out;

    const int* src = ei;
    const int* dst = ei + N_EDGES;

    char* w = (char*)d_ws;
    int*          btot    = (int*)(w + 0);          //   3128 B
    int*          gbase   = (int*)(w + 4096);       //   3128 B
    int*          gcur    = (int*)(w + 8192);       //   3128 B
    float*        dinv    = (float*)(w + 12288);    // 400000 B
    int*          nodeptr = (int*)(w + 412672);     // 400004 B (incl. sentinel)
    unsigned int* hs1b    = (unsigned int*)(w + 815104);   // 3.2 MB (bf16x2)
    unsigned int* hs2b    = (unsigned int*)(w + 4016128);  // 1.6 MB (bf16x2)
    int*          entries = (int*)(w + 5617664);    // 12.8 MB  (total ~18.4 MB)

    k_zero_b  <<<1, 1024, 0, stream>>>(btot);
    k_bhist   <<<NCHUNK, 256, 0, stream>>>(dst, btot);
    k_bscan   <<<1, 1024, 0, stream>>>(btot, gbase, gcur);
    k_bscatter<<<NCHUNK, 256, 0, stream>>>(src, dst, gcur, entries);
    k_nodesort<<<NBUK, 512, 0, stream>>>(entries, btot, gbase, dinv, nodeptr);
    k_gemm1   <<<N_NODES / 16, 256, 0, stream>>>(x, W1, dinv, hs1b);
    k_agg1    <<<NBUK, 512, 0, stream>>>(hs1b, entries, nodeptr, dinv, b1, W2, hs2b);
    k_agg2    <<<NBUK, 512, 0, stream>>>(hs2b, entries, nodeptr, dinv, b2, out);
}

// Round 5
// 514.727 us; speedup vs baseline: 1.8568x; 1.0113x over previous
//
#include <hip/hip_runtime.h>
#include <math.h>

#define N_NODES   100000
#define N_FEAT    512
#define HIDDEN    16
#define N_CLASSES 7
#define N_EDGES   3200000

// bucket = dst >> 7  (128 nodes per bucket)
#define BSHIFT 7
#define BNODES 128
#define BMASK  127
#define NBUK   782            // ceil(100000/128)
#define CHUNK  16384
#define NCHUNK 196            // ceil(3200000/16384)
#define CAP    6144           // LDS stage cap per bucket (mean 4092, sigma~64)

typedef short v8s __attribute__((ext_vector_type(8)));
typedef float v4f __attribute__((ext_vector_type(4)));

__device__ __forceinline__ float bf_lo(unsigned int p) { return __uint_as_float(p << 16); }
__device__ __forceinline__ float bf_hi(unsigned int p) { return __uint_as_float(p & 0xffff0000u); }
__device__ __forceinline__ unsigned int pack_bf2(float a, float b) {
    unsigned int ua = __float_as_uint(a); ua += 0x7fffu + ((ua >> 16) & 1u);
    unsigned int ub = __float_as_uint(b); ub += 0x7fffu + ((ub >> 16) & 1u);
    return (ua >> 16) | (ub & 0xffff0000u);
}

// ---------- pass 1: per-chunk bucket histograms (1 LDS atomic lane / edge) ----------

__global__ __launch_bounds__(256) void k_hist(const int* __restrict__ dst,
                                              int* __restrict__ hglob) {
    __shared__ int h[NBUK];
    int tid = threadIdx.x;
    for (int i = tid; i < NBUK; i += 256) h[i] = 0;
    __syncthreads();
    int base = blockIdx.x * CHUNK;
    for (int i = tid; i < CHUNK; i += 256) {
        int e = base + i;
        if (e < N_EDGES) atomicAdd(&h[dst[e] >> BSHIFT], 1);
    }
    __syncthreads();
    for (int i = tid; i < NBUK; i += 256)
        hglob[blockIdx.x * NBUK + i] = h[i];
}

// ---------- pass 2: column sums -> btot, exclusive scan -> gbase, chunk-prefixed bases -> hpre ----------

__global__ __launch_bounds__(1024) void k_scan(const int* __restrict__ hglob,
                                               int* __restrict__ btot,
                                               int* __restrict__ gbase,
                                               int* __restrict__ hpre) {
    __shared__ int sd[1024];
    int t = threadIdx.x;
    int tot = 0;
    if (t < NBUK)
        for (int c = 0; c < NCHUNK; c++) tot += hglob[c * NBUK + t];
    sd[t] = (t < NBUK) ? tot : 0;
    __syncthreads();
    for (int off = 1; off < 1024; off <<= 1) {
        int a = (t >= off) ? sd[t - off] : 0;
        __syncthreads();
        sd[t] += a;
        __syncthreads();
    }
    if (t < NBUK) {
        int ex = sd[t] - tot;  // exclusive
        btot[t] = tot;
        gbase[t] = ex;
        int run = ex;
        for (int c = 0; c < NCHUNK; c++) {
            hpre[c * NBUK + t] = run;
            run += hglob[c * NBUK + t];
        }
    }
}

// ---------- pass 3: scatter (1 LDS atomic lane / edge, deterministic layout) ----------

__global__ __launch_bounds__(256) void k_scatter(const int* __restrict__ src,
                                                 const int* __restrict__ dst,
                                                 const int* __restrict__ hpre,
                                                 int* __restrict__ entries) {
    __shared__ int lb[NBUK];
    __shared__ int cur[NBUK];
    int tid = threadIdx.x;
    for (int i = tid; i < NBUK; i += 256) {
        lb[i] = hpre[blockIdx.x * NBUK + i];
        cur[i] = 0;
    }
    __syncthreads();
    int base = blockIdx.x * CHUNK;
    for (int i = tid; i < CHUNK; i += 256) {
        int e = base + i;
        if (e < N_EDGES) {
            int d = dst[e];
            int b = d >> BSHIFT;
            int pos = lb[b] + atomicAdd(&cur[b], 1);
            entries[pos] = src[e] | ((d & BMASK) << 17);  // src<2^17, loc 7 bits
        }
    }
}

// ---------- pass 4: in-LDS node-granular counting sort per bucket ----------

__global__ __launch_bounds__(512) void k_nodesort(int* __restrict__ entries,
                                                  const int* __restrict__ btot,
                                                  const int* __restrict__ gbase,
                                                  float* __restrict__ dinv,
                                                  int* __restrict__ nodeptr) {
    __shared__ int ebuf[CAP];
    __shared__ int hcnt[BNODES];
    __shared__ int hincl[BNODES];
    __shared__ int hcur[BNODES];
    int tid = threadIdx.x;
    int bk = blockIdx.x;
    int cnt = btot[bk], base = gbase[bk];
    if (cnt > CAP) cnt = CAP;  // statistically impossible; guards LDS
    if (tid < BNODES) hcnt[tid] = 0;
    __syncthreads();
    for (int i = tid; i < cnt; i += 512) {
        int en = entries[base + i];
        ebuf[i] = en;
        atomicAdd(&hcnt[en >> 17], 1);
    }
    __syncthreads();
    if (tid < BNODES) hincl[tid] = hcnt[tid];
    __syncthreads();
    for (int off = 1; off < BNODES; off <<= 1) {
        int v = 0;
        if (tid < BNODES && tid >= off) v = hincl[tid - off];
        __syncthreads();
        if (tid < BNODES) hincl[tid] += v;
        __syncthreads();
    }
    if (tid < BNODES) {
        int excl = hincl[tid] - hcnt[tid];
        hcur[tid] = excl;
        int n = bk * BNODES + tid;
        if (n < N_NODES) {
            nodeptr[n] = base + excl;
            dinv[n]    = rsqrtf((float)(hcnt[tid] + 1));  // +1 self-loop
        } else if (n == N_NODES) {
            nodeptr[n] = base + excl;  // sentinel == N_EDGES
        }
    }
    __syncthreads();
    for (int i = tid; i < cnt; i += 512) {
        int en = ebuf[i];
        int pos = atomicAdd(&hcur[en >> 17], 1);
        entries[base + pos] = en & 0x1FFFF;  // plain src id
    }
}

// ---------- GEMM1 via MFMA: hs1 = bf16( dinv ⊙ (x @ W1) ) ----------
// block = 256 thr = 4 waves; 64 rows/block; K chunked by 128; A staged bf16 in LDS,
// B (W1) pre-packed into per-(step,lane) fragments in LDS.

__global__ __launch_bounds__(256) void k_gemm1(const float* __restrict__ x,
                                               const float* __restrict__ W1,
                                               const float* __restrict__ dinv,
                                               unsigned int* __restrict__ hs1b) {
    __shared__ unsigned int wfrag[16 * 64 * 4];  // 16 KB: [kstep][lane][4 dwords]
    __shared__ unsigned int atile[64 * 68];      // 17 KB: 64 rows x 136 bf16 (pitch-pad 8)

    int tid = threadIdx.x;
    int wave = tid >> 6, lane = tid & 63;
    int row0 = blockIdx.x * 64;
    int m = lane & 15, quad = lane >> 4;

    // stage W fragments: slot q = kstep*64 + lane
    {
        int q0 = tid * 4;
#pragma unroll
        for (int qq = 0; qq < 4; qq++) {
            int q = q0 + qq;
            int s = q >> 6, l = q & 63;
            int n = l & 15, kb = s * 32 + (l >> 4) * 8;
            unsigned int* wp = &wfrag[q * 4];
#pragma unroll
            for (int h = 0; h < 4; h++)
                wp[h] = pack_bf2(W1[(kb + 2 * h) * 16 + n],
                                 W1[(kb + 2 * h + 1) * 16 + n]);
        }
    }

    v4f acc = {0.f, 0.f, 0.f, 0.f};

    for (int c = 0; c < 4; c++) {
        __syncthreads();
#pragma unroll
        for (int i = 0; i < 8; i++) {
            int f = i * 256 + tid;          // float4 id; 32 per row
            int r = f >> 5, c4 = f & 31;
            int grow = row0 + r;
            float4 xv = make_float4(0.f, 0.f, 0.f, 0.f);
            if (grow < N_NODES)
                xv = *(const float4*)(x + (size_t)grow * N_FEAT + c * 128 + c4 * 4);
            unsigned int* ap = &atile[r * 68 + c4 * 2];
            ap[0] = pack_bf2(xv.x, xv.y);
            ap[1] = pack_bf2(xv.z, xv.w);
        }
        __syncthreads();
#pragma unroll
        for (int s = 0; s < 4; s++) {
            v8s af = *(const v8s*)&atile[(wave * 16 + m) * 68 + s * 16 + quad * 4];
            v8s bf = *(const v8s*)&wfrag[((c * 4 + s) * 64 + lane) * 4];
            acc = __builtin_amdgcn_mfma_f32_16x16x32_bf16(af, bf, acc, 0, 0, 0);
        }
    }

    // epilogue: D[row=quad*4+r][col=lane&15] -> LDS -> packed bf16x2 coalesced store
    __syncthreads();
    float* dt = (float*)atile;
    {
        float* wdt = dt + wave * 272;  // 16*17 floats per wave
        int col = lane & 15;
#pragma unroll
        for (int r = 0; r < 4; r++)
            wdt[(quad * 4 + r) * 17 + col] = acc[r];
    }
    __syncthreads();
    {
        int row = tid >> 2, p = tid & 3;
        int grow = row0 + row;
        if (grow < N_NODES) {
            float dn = dinv[grow];
            float* wdt = dt + (row >> 4) * 272 + (row & 15) * 17 + 4 * p;
            unsigned int d0 = pack_bf2(dn * wdt[0], dn * wdt[1]);
            unsigned int d1 = pack_bf2(dn * wdt[2], dn * wdt[3]);
            *(uint2*)(hs1b + (size_t)grow * 8 + 2 * p) = make_uint2(d0, d1);
        }
    }
}

// ---------- layer1 aggregate (atomic-free) + bias + relu + W2 ----------

__global__ __launch_bounds__(512) void k_agg1(const unsigned int* __restrict__ hs1b,
                                              const int* __restrict__ srt,
                                              const int* __restrict__ nodeptr,
                                              const float* __restrict__ dinv,
                                              const float* __restrict__ b1,
                                              const float* __restrict__ W2,
                                              unsigned int* __restrict__ hs2b) {
    __shared__ float w2l[HIDDEN * N_CLASSES];
    __shared__ float b1l[HIDDEN];
    int tid = threadIdx.x;
    if (tid < HIDDEN * N_CLASSES) w2l[tid] = W2[tid];
    if (tid < HIDDEN) b1l[tid] = b1[tid];
    __syncthreads();

    int bk = blockIdx.x;
    int g = tid >> 3, j = tid & 7;

#pragma unroll
    for (int rep = 0; rep < 2; rep++) {
        int l = g + rep * 64;
        int n = bk * BNODES + l;
        float t[7] = {0.f, 0.f, 0.f, 0.f, 0.f, 0.f, 0.f};
        float dn = 0.f;
        if (n < N_NODES) {
            int p0 = nodeptr[n], p1 = nodeptr[n + 1];
            float aL0 = 0, aH0 = 0, aL1 = 0, aH1 = 0;
            float aL2 = 0, aH2 = 0, aL3 = 0, aH3 = 0;
            int e = p0;
            for (; e + 4 <= p1; e += 4) {
                int s0 = srt[e], s1 = srt[e + 1], s2 = srt[e + 2], s3 = srt[e + 3];
                unsigned int v0 = hs1b[(size_t)s0 * 8 + j];
                unsigned int v1 = hs1b[(size_t)s1 * 8 + j];
                unsigned int v2 = hs1b[(size_t)s2 * 8 + j];
                unsigned int v3 = hs1b[(size_t)s3 * 8 + j];
                aL0 += bf_lo(v0); aH0 += bf_hi(v0);
                aL1 += bf_lo(v1); aH1 += bf_hi(v1);
                aL2 += bf_lo(v2); aH2 += bf_hi(v2);
                aL3 += bf_lo(v3); aH3 += bf_hi(v3);
            }
            for (; e < p1; e++) {
                unsigned int v = hs1b[(size_t)srt[e] * 8 + j];
                aL0 += bf_lo(v); aH0 += bf_hi(v);
            }
            unsigned int sv = hs1b[(size_t)n * 8 + j];  // self-loop
            float accL = aL0 + aL1 + aL2 + aL3 + bf_lo(sv);
            float accH = aH0 + aH1 + aH2 + aH3 + bf_hi(sv);
            dn = dinv[n];
            float z0 = fmaxf(dn * accL + b1l[2 * j],     0.f);
            float z1 = fmaxf(dn * accH + b1l[2 * j + 1], 0.f);
            const float* wr0 = &w2l[(2 * j) * 7];
            const float* wr1 = &w2l[(2 * j + 1) * 7];
#pragma unroll
            for (int q = 0; q < 7; q++) t[q] = z0 * wr0[q] + z1 * wr1[q];
        }
#pragma unroll
        for (int mk = 1; mk < 8; mk <<= 1) {
#pragma unroll
            for (int q = 0; q < 7; q++) t[q] += __shfl_xor(t[q], mk, 64);
        }
        if (j == 0 && n < N_NODES) {
            uint4* o = (uint4*)(hs2b + (size_t)n * 4);
            o[0] = make_uint4(pack_bf2(dn * t[0], dn * t[1]),
                              pack_bf2(dn * t[2], dn * t[3]),
                              pack_bf2(dn * t[4], dn * t[5]),
                              pack_bf2(dn * t[6], 0.f));
        }
    }
}

// ---------- layer2 aggregate (atomic-free) + bias + log_softmax ----------

__global__ __launch_bounds__(512) void k_agg2(const unsigned int* __restrict__ hs2b,
                                              const int* __restrict__ srt,
                                              const int* __restrict__ nodeptr,
                                              const float* __restrict__ dinv,
                                              const float* __restrict__ b2,
                                              float* __restrict__ out) {
    int tid = threadIdx.x;
    int g = tid >> 2, j = tid & 3;
    int bk = blockIdx.x;
    int n = bk * BNODES + g;
    bool valid = (n < N_NODES);
    float lL = -3.4e38f, lH = -3.4e38f;
    if (valid) {
        int p0 = nodeptr[n], p1 = nodeptr[n + 1];
        float aL0 = 0, aH0 = 0, aL1 = 0, aH1 = 0;
        float aL2 = 0, aH2 = 0, aL3 = 0, aH3 = 0;
        int e = p0;
        for (; e + 4 <= p1; e += 4) {
            int s0 = srt[e], s1 = srt[e + 1], s2 = srt[e + 2], s3 = srt[e + 3];
            unsigned int v0 = hs2b[(size_t)s0 * 4 + j];
            unsigned int v1 = hs2b[(size_t)s1 * 4 + j];
            unsigned int v2 = hs2b[(size_t)s2 * 4 + j];
            unsigned int v3 = hs2b[(size_t)s3 * 4 + j];
            aL0 += bf_lo(v0); aH0 += bf_hi(v0);
            aL1 += bf_lo(v1); aH1 += bf_hi(v1);
            aL2 += bf_lo(v2); aH2 += bf_hi(v2);
            aL3 += bf_lo(v3); aH3 += bf_hi(v3);
        }
        for (; e < p1; e++) {
            unsigned int v = hs2b[(size_t)srt[e] * 4 + j];
            aL0 += bf_lo(v); aH0 += bf_hi(v);
        }
        unsigned int sv = hs2b[(size_t)n * 4 + j];  // self-loop
        float accL = aL0 + aL1 + aL2 + aL3 + bf_lo(sv);
        float accH = aH0 + aH1 + aH2 + aH3 + bf_hi(sv);
        float dn = dinv[n];
        lL = dn * accL + b2[2 * j];
        int cch = 2 * j + 1;
        lH = (cch < 7) ? (dn * accH + b2[cch]) : -3.4e38f;
    }
    float mm = fmaxf(lL, lH);
    mm = fmaxf(mm, __shfl_xor(mm, 1, 64));
    mm = fmaxf(mm, __shfl_xor(mm, 2, 64));
    float s = 0.f;
    if (valid) {
        s = expf(lL - mm);
        if (2 * j + 1 < 7) s += expf(lH - mm);
    }
    s += __shfl_xor(s, 1, 64);
    s += __shfl_xor(s, 2, 64);
    if (valid) {
        float ls = mm + logf(s);
        out[(size_t)n * 7 + 2 * j] = lL - ls;
        if (2 * j + 1 < 7) out[(size_t)n * 7 + 2 * j + 1] = lH - ls;
    }
}

// ---------- launch ----------

extern "C" void kernel_launch(void* const* d_in, const int* in_sizes, int n_in,
                              void* d_out, int out_size, void* d_ws, size_t ws_size,
                              hipStream_t stream) {
    const float* x  = (const float*)d_in[0];
    const int*   ei = (const int*)d_in[1];
    const float* W1 = (const float*)d_in[2];
    const float* b1 = (const float*)d_in[3];
    const float* W2 = (const float*)d_in[4];
    const float* b2 = (const float*)d_in[5];
    float* out = (float*)d_out;

    const int* src = ei;
    const int* dst = ei + N_EDGES;

    char* w = (char*)d_ws;
    int*          btot    = (int*)(w + 0);          //   3128 B
    int*          gbase   = (int*)(w + 4096);       //   3128 B
    float*        dinv    = (float*)(w + 8192);     // 400000 B
    int*          nodeptr = (int*)(w + 408576);     // 400004 B (incl. sentinel)
    int*          hglob   = (int*)(w + 808960);     // 613088 B
    int*          hpre    = (int*)(w + 1422336);    // 613088 B
    unsigned int* hs1b    = (unsigned int*)(w + 2036736);  // 3.2 MB (bf16x2)
    unsigned int* hs2b    = (unsigned int*)(w + 5236736);  // 1.6 MB (bf16x2)
    int*          entries = (int*)(w + 6836736);    // 12.8 MB  (total ~19.6 MB)

    k_hist    <<<NCHUNK, 256, 0, stream>>>(dst, hglob);
    k_scan    <<<1, 1024, 0, stream>>>(hglob, btot, gbase, hpre);
    k_scatter <<<NCHUNK, 256, 0, stream>>>(src, dst, hpre, entries);
    k_nodesort<<<NBUK, 512, 0, stream>>>(entries, btot, gbase, dinv, nodeptr);
    k_gemm1   <<<1563, 256, 0, stream>>>(x, W1, dinv, hs1b);
    k_agg1    <<<NBUK, 512, 0, stream>>>(hs1b, entries, nodeptr, dinv, b1, W2, hs2b);
    k_agg2    <<<NBUK, 512, 0, stream>>>(hs2b, entries, nodeptr, dinv, b2, out);
}